// Round 1
// baseline (1296.914 us; speedup 1.0000x reference)
//
#include <hip/hip_runtime.h>
#include <hip/hip_bf16.h>
#include <cstdint>
#include <cstddef>

// Problem constants (from reference)
#define NPTS  1000000
#define BSEG  2000
#define DIN   16
#define HDIM  256
#define DOUT  128

typedef __bf16          bf16x8 __attribute__((ext_vector_type(8)));
typedef unsigned short  us16x8 __attribute__((ext_vector_type(8)));
typedef unsigned int    u32x4  __attribute__((ext_vector_type(4)));
typedef float           f32x4  __attribute__((ext_vector_type(4)));

static __device__ __forceinline__ unsigned short f2bf(float x) {
    // fp32 -> bf16 round-to-nearest-even (inputs are finite Gaussians; no NaN path)
    unsigned int u = __float_as_uint(x);
    u += 0x7fffu + ((u >> 16) & 1u);
    return (unsigned short)(u >> 16);
}
static __device__ __forceinline__ float bflo(unsigned int u) { return __uint_as_float(u << 16); }
static __device__ __forceinline__ float bfhi(unsigned int u) { return __uint_as_float(u & 0xffff0000u); }

static __device__ __forceinline__ bf16x8 ldb8(const unsigned short* p) {
    u32x4 v = *(const u32x4*)p;               // 16B vector load (global or LDS)
    return __builtin_bit_cast(bf16x8, v);
}
static __device__ __forceinline__ f32x4 mfma16(bf16x8 a, bf16x8 b, f32x4 c) {
    return __builtin_amdgcn_mfma_f32_16x16x32_bf16(a, b, c, 0, 0, 0);
}

// ---------------------------------------------------------------------------
// Prefix scan of counts -> exclusive offsets[0..B]   (single block, 1024 thr)
// ---------------------------------------------------------------------------
__global__ __launch_bounds__(1024) void scan_counts(const int* __restrict__ counts,
                                                    int* __restrict__ offsets) {
    __shared__ int a[2048];
    const int t = threadIdx.x;
    a[t]        = (t        < BSEG) ? counts[t]        : 0;
    a[t + 1024] = (t + 1024 < BSEG) ? counts[t + 1024] : 0;
    for (int s = 1; s < 2048; s <<= 1) {
        __syncthreads();
        int x1 = (t >= s) ? a[t - s] : 0;
        int x2 = a[t + 1024 - s];
        __syncthreads();
        a[t] += x1;
        a[t + 1024] += x2;
    }
    __syncthreads();
    if (t == 0) offsets[0] = 0;
    offsets[t + 1] = a[t];                               // 1..1024
    if (t + 1024 < BSEG) offsets[t + 1025] = a[t + 1024]; // 1025..2000
}

// ---------------------------------------------------------------------------
// seg[i] = b for i in [offsets[b], offsets[b+1])
// ---------------------------------------------------------------------------
__global__ __launch_bounds__(256) void fill_seg(const int* __restrict__ offsets,
                                                int* __restrict__ seg) {
    const int b  = blockIdx.x;
    const int lo = offsets[b], hi = offsets[b + 1];
    for (int i = lo + threadIdx.x; i < hi; i += 256) seg[i] = b;
}

// ---------------------------------------------------------------------------
// Transpose+convert weights to bf16, [n][k]-major so MFMA B-frags are
// 16B-contiguous: lane reads W^T[n = lane&15 + 16*nt][k = quad*8 + j].
// W1 K padded 16->32 with zeros.
// ---------------------------------------------------------------------------
__global__ __launch_bounds__(256) void prep_weights(const float* __restrict__ W1,
                                                    const float* __restrict__ W2,
                                                    const float* __restrict__ W3,
                                                    unsigned short* __restrict__ w1t,
                                                    unsigned short* __restrict__ w2t,
                                                    unsigned short* __restrict__ w3t) {
    const int i = blockIdx.x * 256 + threadIdx.x;
    if (i < HDIM * 32) {                                  // W1T [256][32]
        int n = i >> 5, k = i & 31;
        w1t[i] = (k < DIN) ? f2bf(W1[k * HDIM + n]) : (unsigned short)0;
    } else if (i < HDIM * 32 + HDIM * HDIM) {             // W2T [256][256]
        int j = i - HDIM * 32;
        int n = j >> 8, k = j & 255;
        w2t[j] = f2bf(W2[k * HDIM + n]);
    } else if (i < HDIM * 32 + HDIM * HDIM + DOUT * HDIM) { // W3T [128][256]
        int j = i - HDIM * 32 - HDIM * HDIM;
        int n = j >> 8, k = j & 255;
        w3t[j] = f2bf(W3[k * DOUT + n]);
    }
}

// ---------------------------------------------------------------------------
// LayerNorm + ReLU in place on a [64][264] bf16 LDS tile.
// 32 lanes per row (ushort8 chunk each); row sums via shfl_xor (masks<=16
// keep lanes within their 32-lane row group). No LDS cross-thread deps.
// ---------------------------------------------------------------------------
__device__ __forceinline__ void ln_relu_pass(unsigned short (*h)[264],
                                             const float* __restrict__ g,
                                             const float* __restrict__ be,
                                             int wave, int lane) {
    const int half  = lane >> 5;
    const int chunk = lane & 31;
    const int c0    = chunk * 8;
    float gr[8], br[8];
#pragma unroll
    for (int i = 0; i < 8; ++i) { gr[i] = g[c0 + i]; br[i] = be[c0 + i]; } // coalesced, L1-hot
#pragma unroll
    for (int it = 0; it < 8; ++it) {
        const int row = wave * 16 + it * 2 + half;
        u32x4 v = *(const u32x4*)&h[row][c0];
        float f[8];
        f[0] = bflo(v[0]); f[1] = bfhi(v[0]);
        f[2] = bflo(v[1]); f[3] = bfhi(v[1]);
        f[4] = bflo(v[2]); f[5] = bfhi(v[2]);
        f[6] = bflo(v[3]); f[7] = bfhi(v[3]);
        float s = 0.f, q = 0.f;
#pragma unroll
        for (int i = 0; i < 8; ++i) { s += f[i]; q += f[i] * f[i]; }
#pragma unroll
        for (int m = 1; m <= 16; m <<= 1) {
            s += __shfl_xor(s, m, 64);
            q += __shfl_xor(q, m, 64);
        }
        const float mean = s * (1.f / 256.f);
        const float rs   = rsqrtf(fmaxf(q * (1.f / 256.f) - mean * mean, 0.f) + 1e-5f);
        u32x4 o;
#pragma unroll
        for (int i = 0; i < 4; ++i) {
            float y0 = fmaxf((f[2*i]   - mean) * rs * gr[2*i]   + br[2*i],   0.f);
            float y1 = fmaxf((f[2*i+1] - mean) * rs * gr[2*i+1] + br[2*i+1], 0.f);
            o[i] = (unsigned)f2bf(y0) | ((unsigned)f2bf(y1) << 16);
        }
        *(u32x4*)&h[row][c0] = o;
    }
}

// ---------------------------------------------------------------------------
// Fused per-point MLP (bf16 MFMA) + ragged segment partial-sum.
// WG = 256 threads (4 waves), tile M = 64 points (grid 15625, exact).
// Wave w owns n-tiles [w*4, w*4+4) for H=256 layers, [w*2, w*2+2) for D_OUT.
// MFMA layouts (doc-verified): A[m=lane&15][k=quad*8+j];
// B[k=quad*8+j][n=lane&15] (from W^T row-major); D[row=quad*4+reg][col=lane&15].
// ---------------------------------------------------------------------------
__global__ __launch_bounds__(256, 2) void fused_phi_pool(
    const float* __restrict__ z,
    const unsigned short* __restrict__ w1t,
    const unsigned short* __restrict__ w2t,
    const unsigned short* __restrict__ w3t,
    const float* __restrict__ b1, const float* __restrict__ g1, const float* __restrict__ be1,
    const float* __restrict__ b2, const float* __restrict__ g2, const float* __restrict__ be2,
    const float* __restrict__ b3,
    const int* __restrict__ seg,
    float* __restrict__ sums) {
    // 264 = 256 + 8 bf16 pad (row stride 528 B) to break LDS bank alignment
    __shared__ __align__(16) unsigned short h1[64][264];
    __shared__ __align__(16) unsigned short h2[64][264];
    __shared__ int seg_sm[64];

    const int tid    = threadIdx.x;
    const int wave   = tid >> 6;
    const int lane   = tid & 63;
    const int l15    = lane & 15;
    const int quad   = lane >> 4;
    const int wgbase = blockIdx.x * 64;

    if (tid < 64) seg_sm[tid] = seg[wgbase + tid];

    // ---- layer 1: h1 = relu(LN(z @ W1 + b1)) ; K=16 zero-padded to 32 ----
    {
        bf16x8 bw[4];
#pragma unroll
        for (int t = 0; t < 4; ++t) {
            int n = (wave * 4 + t) * 16 + l15;
            bw[t] = ldb8(w1t + n * 32 + quad * 8);
        }
#pragma unroll
        for (int mb = 0; mb < 4; ++mb) {
            bf16x8 af;
            if (quad < 2) {   // k = quad*8 + j < 16 valid
                const float* zp = z + (size_t)(wgbase + mb * 16 + l15) * DIN + quad * 8;
                float4 v0 = *(const float4*)(zp);
                float4 v1 = *(const float4*)(zp + 4);
                us16x8 u;
                u[0] = f2bf(v0.x); u[1] = f2bf(v0.y); u[2] = f2bf(v0.z); u[3] = f2bf(v0.w);
                u[4] = f2bf(v1.x); u[5] = f2bf(v1.y); u[6] = f2bf(v1.z); u[7] = f2bf(v1.w);
                af = __builtin_bit_cast(bf16x8, u);
            } else {          // zero-padded K region
                us16x8 u = {0, 0, 0, 0, 0, 0, 0, 0};
                af = __builtin_bit_cast(bf16x8, u);
            }
            f32x4 acc[4] = {};
#pragma unroll
            for (int t = 0; t < 4; ++t) acc[t] = mfma16(af, bw[t], acc[t]);
#pragma unroll
            for (int t = 0; t < 4; ++t) {
                int col = (wave * 4 + t) * 16 + l15;
                float bias = b1[col];
#pragma unroll
                for (int r = 0; r < 4; ++r)
                    h1[mb * 16 + quad * 4 + r][col] = f2bf(acc[t][r] + bias);
            }
        }
    }
    __syncthreads();
    ln_relu_pass(h1, g1, be1, wave, lane);
    __syncthreads();

    // ---- layer 2: h2 = relu(LN(h1 @ W2 + b2)) ----
    {
        bf16x8 bw[4][8];          // 4 n-tiles x 8 k-steps, register-cached
#pragma unroll
        for (int t = 0; t < 4; ++t) {
            const unsigned short* base = w2t + ((wave * 4 + t) * 16 + l15) * 256 + quad * 8;
#pragma unroll
            for (int ks = 0; ks < 8; ++ks) bw[t][ks] = ldb8(base + ks * 32);
        }
#pragma unroll
        for (int mb = 0; mb < 4; ++mb) {
            bf16x8 af[8];
#pragma unroll
            for (int ks = 0; ks < 8; ++ks)
                af[ks] = ldb8(&h1[mb * 16 + l15][ks * 32 + quad * 8]);
            f32x4 acc[4] = {};
#pragma unroll
            for (int ks = 0; ks < 8; ++ks)   // ks outer: 4 independent MFMA chains
#pragma unroll
                for (int t = 0; t < 4; ++t) acc[t] = mfma16(af[ks], bw[t][ks], acc[t]);
#pragma unroll
            for (int t = 0; t < 4; ++t) {
                int col = (wave * 4 + t) * 16 + l15;
                float bias = b2[col];
#pragma unroll
                for (int r = 0; r < 4; ++r)
                    h2[mb * 16 + quad * 4 + r][col] = f2bf(acc[t][r] + bias);
            }
        }
    }
    __syncthreads();
    ln_relu_pass(h2, g2, be2, wave, lane);
    __syncthreads();

    // ---- layer 3: phi = h2 @ W3 + b3 (fp32, into h1's LDS, stride 132 f32) ----
    float* phi = reinterpret_cast<float*>(&h1[0][0]);
    {
        bf16x8 bw[2][8];
#pragma unroll
        for (int t = 0; t < 2; ++t) {
            const unsigned short* base = w3t + ((wave * 2 + t) * 16 + l15) * 256 + quad * 8;
#pragma unroll
            for (int ks = 0; ks < 8; ++ks) bw[t][ks] = ldb8(base + ks * 32);
        }
#pragma unroll
        for (int mb = 0; mb < 4; ++mb) {
            bf16x8 af[8];
#pragma unroll
            for (int ks = 0; ks < 8; ++ks)
                af[ks] = ldb8(&h2[mb * 16 + l15][ks * 32 + quad * 8]);
            f32x4 acc[2] = {};
#pragma unroll
            for (int ks = 0; ks < 8; ++ks)
#pragma unroll
                for (int t = 0; t < 2; ++t) acc[t] = mfma16(af[ks], bw[t][ks], acc[t]);
#pragma unroll
            for (int t = 0; t < 2; ++t) {
                int col = (wave * 2 + t) * 16 + l15;
                float bias = b3[col];
#pragma unroll
                for (int r = 0; r < 4; ++r)
                    phi[(mb * 16 + quad * 4 + r) * 132 + col] = acc[t][r] + bias;
            }
        }
    }
    __syncthreads();

    // ---- ragged segment partial sums: run-accumulate, one atomic per run ----
    {
        const int c    = tid & 127;
        const int half = tid >> 7;             // rows [half*32, half*32+32)
        int   cur = seg_sm[half * 32];
        float run = 0.f;
        for (int i = 0; i < 32; ++i) {
            int m = half * 32 + i;
            int s = seg_sm[m];                 // wave-uniform -> no divergence
            if (s != cur) {
                atomicAdd(&sums[cur * DOUT + c], run);
                run = 0.f;
                cur = s;
            }
            run += phi[m * 132 + c];
        }
        atomicAdd(&sums[cur * DOUT + c], run);
    }
}

// ---------------------------------------------------------------------------
// emb = sums / count
// ---------------------------------------------------------------------------
__global__ __launch_bounds__(256) void normalize_emb(const float* __restrict__ sums,
                                                     const int* __restrict__ counts,
                                                     float* __restrict__ emb) {
    const int i = blockIdx.x * 256 + threadIdx.x;   // exactly B*DOUT
    const int b = i >> 7;
    emb[i] = sums[i] / (float)counts[b];
}

// ---------------------------------------------------------------------------
// out[n] = emb[seg[n]] ; float4 per thread, perfectly coalesced stores
// ---------------------------------------------------------------------------
__global__ __launch_bounds__(256) void broadcast_out(const float* __restrict__ emb,
                                                     const int* __restrict__ seg,
                                                     float* __restrict__ out) {
    const int idx = blockIdx.x * 256 + threadIdx.x;  // n*32 + q, exactly N*32
    const int n = idx >> 5, q = idx & 31;
    const int s = seg[n];
    ((float4*)out)[idx] = ((const float4*)emb)[s * 32 + q];
}

// ---------------------------------------------------------------------------
extern "C" void kernel_launch(void* const* d_in, const int* in_sizes, int n_in,
                              void* d_out, int out_size, void* d_ws, size_t ws_size,
                              hipStream_t stream) {
    const float* z   = (const float*)d_in[0];
    const float* W1  = (const float*)d_in[1];
    const float* b1  = (const float*)d_in[2];
    const float* g1  = (const float*)d_in[3];
    const float* be1 = (const float*)d_in[4];
    const float* W2  = (const float*)d_in[5];
    const float* b2  = (const float*)d_in[6];
    const float* g2  = (const float*)d_in[7];
    const float* be2 = (const float*)d_in[8];
    const float* W3  = (const float*)d_in[9];
    const float* b3  = (const float*)d_in[10];
    const int*  counts = (const int*)d_in[11];   // jnp int64 is x32-downcast -> int32
    float* out = (float*)d_out;

    // workspace layout (all 16B aligned)
    char* ws = (char*)d_ws;
    float* sums          = (float*)(ws);                  // 1,024,000 B
    float* emb           = (float*)(ws + 1024000);        // 1,024,000 B
    int*   offsets       = (int*)  (ws + 2048000);        //     8,016 B
    int*   seg           = (int*)  (ws + 2056016);        // 4,000,000 B
    unsigned short* w1t  = (unsigned short*)(ws + 6056016); //  16,384 B
    unsigned short* w2t  = (unsigned short*)(ws + 6072400); // 131,072 B
    unsigned short* w3t  = (unsigned short*)(ws + 6203472); //  65,536 B

    hipMemsetAsync(sums, 0, (size_t)BSEG * DOUT * sizeof(float), stream);
    scan_counts<<<1, 1024, 0, stream>>>(counts, offsets);
    fill_seg<<<BSEG, 256, 0, stream>>>(offsets, seg);
    prep_weights<<<(HDIM * 32 + HDIM * HDIM + DOUT * HDIM + 255) / 256, 256, 0, stream>>>(
        W1, W2, W3, w1t, w2t, w3t);
    fused_phi_pool<<<NPTS / 64, 256, 0, stream>>>(z, w1t, w2t, w3t,
                                                  b1, g1, be1, b2, g2, be2, b3,
                                                  seg, sums);
    normalize_emb<<<BSEG * DOUT / 256, 256, 0, stream>>>(sums, counts, emb);
    broadcast_out<<<NPTS * 32 / 256, 256, 0, stream>>>(emb, seg, out);
}

// Round 2
// 1068.274 us; speedup vs baseline: 1.2140x; 1.2140x over previous
//
#include <hip/hip_runtime.h>
#include <hip/hip_bf16.h>
#include <cstdint>
#include <cstddef>

// Problem constants (from reference)
#define NPTS  1000000
#define BSEG  2000
#define DIN   16
#define HDIM  256
#define DOUT  128
#define NTILE (NPTS / 32)   // 31250 tiles of 32 points
#define NWG   512           // persistent workgroups (2/CU target)

typedef __bf16          bf16x8 __attribute__((ext_vector_type(8)));
typedef unsigned short  us16x8 __attribute__((ext_vector_type(8)));
typedef unsigned int    u32x4  __attribute__((ext_vector_type(4)));
typedef float           f32x4  __attribute__((ext_vector_type(4)));

static __device__ __forceinline__ unsigned short f2bf(float x) {
    unsigned int u = __float_as_uint(x);
    u += 0x7fffu + ((u >> 16) & 1u);
    return (unsigned short)(u >> 16);
}

static __device__ __forceinline__ bf16x8 ldb8(const unsigned short* p) {
    u32x4 v = *(const u32x4*)p;
    return __builtin_bit_cast(bf16x8, v);
}
static __device__ __forceinline__ f32x4 mfma16(bf16x8 a, bf16x8 b, f32x4 c) {
    return __builtin_amdgcn_mfma_f32_16x16x32_bf16(a, b, c, 0, 0, 0);
}
// Pin a fragment in VGPRs: the asm "modifies" the value, so the compiler
// cannot rematerialize the originating load inside the persistent loop.
static __device__ __forceinline__ void keep(bf16x8& v) {
    u32x4 u = __builtin_bit_cast(u32x4, v);
    unsigned a0 = u[0], a1 = u[1], a2 = u[2], a3 = u[3];
    asm volatile("" : "+v"(a0), "+v"(a1), "+v"(a2), "+v"(a3));
    u32x4 r; r[0] = a0; r[1] = a1; r[2] = a2; r[3] = a3;
    v = __builtin_bit_cast(bf16x8, r);
}

// ---------------------------------------------------------------------------
// Prefix scan of counts -> exclusive offsets[0..B]
// ---------------------------------------------------------------------------
__global__ __launch_bounds__(1024) void scan_counts(const int* __restrict__ counts,
                                                    int* __restrict__ offsets) {
    __shared__ int a[2048];
    const int t = threadIdx.x;
    a[t]        = (t        < BSEG) ? counts[t]        : 0;
    a[t + 1024] = (t + 1024 < BSEG) ? counts[t + 1024] : 0;
    for (int s = 1; s < 2048; s <<= 1) {
        __syncthreads();
        int x1 = (t >= s) ? a[t - s] : 0;
        int x2 = a[t + 1024 - s];
        __syncthreads();
        a[t] += x1;
        a[t + 1024] += x2;
    }
    __syncthreads();
    if (t == 0) offsets[0] = 0;
    offsets[t + 1] = a[t];
    if (t + 1024 < BSEG) offsets[t + 1025] = a[t + 1024];
}

__global__ __launch_bounds__(256) void fill_seg(const int* __restrict__ offsets,
                                                unsigned short* __restrict__ seg) {
    const int b  = blockIdx.x;
    const int lo = offsets[b], hi = offsets[b + 1];
    for (int i = lo + threadIdx.x; i < hi; i += 256) seg[i] = (unsigned short)b;
}

// W1T [256][32] (K zero-padded 16->32), W2T [256][256]; [n][k]-major bf16.
__global__ __launch_bounds__(256) void prep_weights(const float* __restrict__ W1,
                                                    const float* __restrict__ W2,
                                                    unsigned short* __restrict__ w1t,
                                                    unsigned short* __restrict__ w2t) {
    const int i = blockIdx.x * 256 + threadIdx.x;
    if (i < HDIM * 32) {
        int n = i >> 5, k = i & 31;
        w1t[i] = (k < DIN) ? f2bf(W1[k * HDIM + n]) : (unsigned short)0;
    } else {
        int j = i - HDIM * 32;
        if (j < HDIM * HDIM) {
            int n = j >> 8, k = j & 255;
            w2t[j] = f2bf(W2[k * HDIM + n]);
        }
    }
}

// ---------------------------------------------------------------------------
// Persistent fused kernel: layer1 -> LN -> ReLU -> layer2 -> LN -> ReLU ->
// ragged segment-sum of h2 (256-dim, fp32 from registers).
// Tile M=32 points, 4 waves; wave w owns cols [w*64, w*64+64).
// Weights register-resident (bw1 16 + bw2 128 VGPRs), pinned via keep().
// MFMA layouts: A[m=lane&15][k=quad*8+j]; B[k=quad*8+j][n=lane&15];
// D[row=quad*4+reg][col=lane&15].
// ---------------------------------------------------------------------------
__global__ __launch_bounds__(256, 2) void fused_phi_pool(
    const float* __restrict__ z,
    const unsigned short* __restrict__ w1t,
    const unsigned short* __restrict__ w2t,
    const float* __restrict__ b1, const float* __restrict__ g1, const float* __restrict__ be1,
    const float* __restrict__ b2, const float* __restrict__ g2, const float* __restrict__ be2,
    const unsigned short* __restrict__ seg,
    float* __restrict__ sums_h) {
    __shared__ __align__(16) unsigned short h1[32][264];   // 16.9 KB
    __shared__ __align__(16) float part[2][32][8];          // [p][row][wave*2+{s,q}]
    __shared__ __align__(16) int seg_sm[2][32];

    const int tid  = threadIdx.x;
    const int wave = tid >> 6;
    const int lane = tid & 63;
    const int l15  = lane & 15;
    const int quad = lane >> 4;
    const int colw = wave * 64 + l15;     // + t*16 gives this lane's cols

    // ---- one-time: register-resident weight fragments ----
    bf16x8 bw1[4];
    bf16x8 bw2[4][8];
#pragma unroll
    for (int t = 0; t < 4; ++t) {
        const int n = (wave * 4 + t) * 16 + l15;
        bw1[t] = ldb8(w1t + n * 32 + quad * 8);
        keep(bw1[t]);
#pragma unroll
        for (int ks = 0; ks < 8; ++ks) {
            bw2[t][ks] = ldb8(w2t + n * 256 + ks * 32 + quad * 8);
            keep(bw2[t][ks]);
        }
    }
    float b1v[4], g1v[4], e1v[4], b2v[4], g2v[4], e2v[4];
#pragma unroll
    for (int t = 0; t < 4; ++t) {
        const int c = colw + t * 16;
        b1v[t] = b1[c]; g1v[t] = g1[c]; e1v[t] = be1[c];
        b2v[t] = b2[c]; g2v[t] = g2[c]; e2v[t] = be2[c];
    }

    int p = 0;
    for (int tile = blockIdx.x; tile < NTILE; tile += NWG, p ^= 1) {
        const int base = tile * 32;
        if (tid < 32) seg_sm[p][tid] = (int)seg[base + tid];   // wave 0

        // ---------------- layer 1 (K=16 zero-padded to 32) ----------------
        f32x4 a1[2][4];
#pragma unroll
        for (int mb = 0; mb < 2; ++mb) {
            bf16x8 af;
            if (quad < 2) {
                const float* zp = z + (size_t)(base + mb * 16 + l15) * DIN + quad * 8;
                float4 v0 = *(const float4*)zp;
                float4 v1 = *(const float4*)(zp + 4);
                us16x8 u;
                u[0] = f2bf(v0.x); u[1] = f2bf(v0.y); u[2] = f2bf(v0.z); u[3] = f2bf(v0.w);
                u[4] = f2bf(v1.x); u[5] = f2bf(v1.y); u[6] = f2bf(v1.z); u[7] = f2bf(v1.w);
                af = __builtin_bit_cast(bf16x8, u);
            } else {
                us16x8 u = {0, 0, 0, 0, 0, 0, 0, 0};
                af = __builtin_bit_cast(bf16x8, u);
            }
            const f32x4 zero = {0.f, 0.f, 0.f, 0.f};
#pragma unroll
            for (int t = 0; t < 4; ++t) a1[mb][t] = mfma16(af, bw1[t], zero);
        }
        // bias + LN stats partials (per-row sum/sumsq over this wave's 64 cols)
#pragma unroll
        for (int mb = 0; mb < 2; ++mb) {
            float s[4], q[4];
#pragma unroll
            for (int r = 0; r < 4; ++r) {
                float sv = 0.f, qv = 0.f;
#pragma unroll
                for (int t = 0; t < 4; ++t) {
                    float y = a1[mb][t][r] + b1v[t];
                    a1[mb][t][r] = y;
                    sv += y; qv += y * y;
                }
                s[r] = sv; q[r] = qv;
            }
#pragma unroll
            for (int m = 1; m <= 8; m <<= 1) {
#pragma unroll
                for (int r = 0; r < 4; ++r) {
                    s[r] += __shfl_xor(s[r], m, 64);
                    q[r] += __shfl_xor(q[r], m, 64);
                }
            }
            if (l15 == 0) {
#pragma unroll
                for (int r = 0; r < 4; ++r)
                    *(float2*)&part[p][mb * 16 + quad * 4 + r][wave * 2] =
                        make_float2(s[r], q[r]);
            }
        }
        __syncthreads();   // B1: stats visible; prior-iter h1 readers done
        // normalize + relu -> bf16 h1 (the D->A transpose store)
#pragma unroll
        for (int mb = 0; mb < 2; ++mb) {
#pragma unroll
            for (int r = 0; r < 4; ++r) {
                const int row = mb * 16 + quad * 4 + r;
                float4 pa = *(const float4*)&part[p][row][0];
                float4 pb = *(const float4*)&part[p][row][4];
                float st = pa.x + pa.z + pb.x + pb.z;
                float qt = pa.y + pa.w + pb.y + pb.w;
                float mean = st * (1.f / 256.f);
                float var  = qt * (1.f / 256.f) - mean * mean;
                float rs   = rsqrtf(fmaxf(var, 0.f) + 1e-5f);
#pragma unroll
                for (int t = 0; t < 4; ++t) {
                    float A = rs * g1v[t];
                    float y = fmaxf(fmaf(a1[mb][t][r], A, fmaf(-mean, A, e1v[t])), 0.f);
                    h1[row][colw + t * 16] = f2bf(y);
                }
            }
        }
        __syncthreads();   // B2: h1 ready

        // ---------------- layer 2 ----------------
        f32x4 a2[2][4];
#pragma unroll
        for (int mb = 0; mb < 2; ++mb) {
            const f32x4 zero = {0.f, 0.f, 0.f, 0.f};
#pragma unroll
            for (int t = 0; t < 4; ++t) a2[mb][t] = zero;
#pragma unroll
            for (int ks = 0; ks < 8; ++ks) {
                bf16x8 af = ldb8(&h1[mb * 16 + l15][ks * 32 + quad * 8]);
#pragma unroll
                for (int t = 0; t < 4; ++t) a2[mb][t] = mfma16(af, bw2[t][ks], a2[mb][t]);
            }
        }
        // bias + LN stats partials
#pragma unroll
        for (int mb = 0; mb < 2; ++mb) {
            float s[4], q[4];
#pragma unroll
            for (int r = 0; r < 4; ++r) {
                float sv = 0.f, qv = 0.f;
#pragma unroll
                for (int t = 0; t < 4; ++t) {
                    float y = a2[mb][t][r] + b2v[t];
                    a2[mb][t][r] = y;
                    sv += y; qv += y * y;
                }
                s[r] = sv; q[r] = qv;
            }
#pragma unroll
            for (int m = 1; m <= 8; m <<= 1) {
#pragma unroll
                for (int r = 0; r < 4; ++r) {
                    s[r] += __shfl_xor(s[r], m, 64);
                    q[r] += __shfl_xor(q[r], m, 64);
                }
            }
            if (l15 == 0) {
#pragma unroll
                for (int r = 0; r < 4; ++r)
                    *(float2*)&part[p][mb * 16 + quad * 4 + r][wave * 2] =
                        make_float2(s[r], q[r]);
            }
        }
        __syncthreads();   // B3: layer-2 stats visible
        // normalize + relu in registers (h2 never hits LDS)
#pragma unroll
        for (int mb = 0; mb < 2; ++mb) {
#pragma unroll
            for (int r = 0; r < 4; ++r) {
                const int row = mb * 16 + quad * 4 + r;
                float4 pa = *(const float4*)&part[p][row][0];
                float4 pb = *(const float4*)&part[p][row][4];
                float st = pa.x + pa.z + pb.x + pb.z;
                float qt = pa.y + pa.w + pb.y + pb.w;
                float mean = st * (1.f / 256.f);
                float var  = qt * (1.f / 256.f) - mean * mean;
                float rs   = rsqrtf(fmaxf(var, 0.f) + 1e-5f);
#pragma unroll
                for (int t = 0; t < 4; ++t) {
                    float A = rs * g2v[t];
                    a2[mb][t][r] =
                        fmaxf(fmaf(a2[mb][t][r], A, fmaf(-mean, A, e2v[t])), 0.f);
                }
            }
        }

        // ---------------- ragged segment-sum of h2 (fp32) ----------------
        const int s0  = seg_sm[p][0];
        const int s31 = seg_sm[p][31];
        if (s0 == s31) {   // tile entirely inside one segment (~94% of tiles)
#pragma unroll
            for (int t = 0; t < 4; ++t) {
                float cs = a2[0][t][0] + a2[0][t][1] + a2[0][t][2] + a2[0][t][3]
                         + a2[1][t][0] + a2[1][t][1] + a2[1][t][2] + a2[1][t][3];
                cs += __shfl_xor(cs, 16, 64);
                cs += __shfl_xor(cs, 32, 64);
                if (quad == 0)
                    atomicAdd(&sums_h[s0 * HDIM + colw + t * 16], cs);
            }
        } else {           // exactly 2 segments (min count 100 > 32)
            const int* sgp = &seg_sm[p][0];
            float m0[4], m1[4];
#pragma unroll
            for (int r = 0; r < 4; ++r) {
                m0[r] = (sgp[quad * 4 + r]      == s0) ? 1.f : 0.f;
                m1[r] = (sgp[16 + quad * 4 + r] == s0) ? 1.f : 0.f;
            }
#pragma unroll
            for (int t = 0; t < 4; ++t) {
                float cs = 0.f, ca = 0.f;
#pragma unroll
                for (int r = 0; r < 4; ++r) {
                    cs += a2[0][t][r] + a2[1][t][r];
                    ca = fmaf(a2[0][t][r], m0[r], ca);
                    ca = fmaf(a2[1][t][r], m1[r], ca);
                }
                cs += __shfl_xor(cs, 16, 64);
                cs += __shfl_xor(cs, 32, 64);
                ca += __shfl_xor(ca, 16, 64);
                ca += __shfl_xor(ca, 32, 64);
                if (quad == 0) {
                    atomicAdd(&sums_h[s0  * HDIM + colw + t * 16], ca);
                    atomicAdd(&sums_h[s31 * HDIM + colw + t * 16], cs - ca);
                }
            }
        }
    }
}

// ---------------------------------------------------------------------------
// emb[b] = (sums_h[b] @ W3) / count_b + b3   (fp32; W3 read straight from input)
// ---------------------------------------------------------------------------
__global__ __launch_bounds__(256) void emb_gemm(const float* __restrict__ sums_h,
                                                const float* __restrict__ W3,
                                                const float* __restrict__ b3,
                                                const int* __restrict__ counts,
                                                float* __restrict__ emb) {
    const int b = blockIdx.x * 2 + (threadIdx.x >> 7);
    const int o = threadIdx.x & 127;
    const float* sh = sums_h + b * HDIM;
    float acc = 0.f;
#pragma unroll 8
    for (int k = 0; k < HDIM; ++k) acc = fmaf(sh[k], W3[k * DOUT + o], acc);
    emb[b * DOUT + o] = acc / (float)counts[b] + b3[o];
}

// ---------------------------------------------------------------------------
// out[n] = emb[seg[n]] ; float4/thread, coalesced
// ---------------------------------------------------------------------------
__global__ __launch_bounds__(256) void broadcast_out(const float* __restrict__ emb,
                                                     const unsigned short* __restrict__ seg,
                                                     float* __restrict__ out) {
    const int idx = blockIdx.x * 256 + threadIdx.x;
    const int n = idx >> 5, qd = idx & 31;
    const int s = seg[n];
    ((float4*)out)[idx] = ((const float4*)emb)[s * 32 + qd];
}

// ---------------------------------------------------------------------------
extern "C" void kernel_launch(void* const* d_in, const int* in_sizes, int n_in,
                              void* d_out, int out_size, void* d_ws, size_t ws_size,
                              hipStream_t stream) {
    const float* z   = (const float*)d_in[0];
    const float* W1  = (const float*)d_in[1];
    const float* b1  = (const float*)d_in[2];
    const float* g1  = (const float*)d_in[3];
    const float* be1 = (const float*)d_in[4];
    const float* W2  = (const float*)d_in[5];
    const float* b2  = (const float*)d_in[6];
    const float* g2  = (const float*)d_in[7];
    const float* be2 = (const float*)d_in[8];
    const float* W3  = (const float*)d_in[9];
    const float* b3  = (const float*)d_in[10];
    const int* counts = (const int*)d_in[11];
    float* out = (float*)d_out;

    // workspace layout (16B aligned)
    char* ws = (char*)d_ws;
    float*          sums_h  = (float*)(ws);                     // 2,048,000 B
    float*          emb     = (float*)(ws + 2048000);           // 1,024,000 B
    int*            offsets = (int*)  (ws + 3072000);           //     8,016 B
    unsigned short* seg     = (unsigned short*)(ws + 3080016);  // 2,000,000 B
    unsigned short* w1t     = (unsigned short*)(ws + 5080016);  //    16,384 B
    unsigned short* w2t     = (unsigned short*)(ws + 5096400);  //   131,072 B

    hipMemsetAsync(sums_h, 0, (size_t)BSEG * HDIM * sizeof(float), stream);
    scan_counts<<<1, 1024, 0, stream>>>(counts, offsets);
    fill_seg<<<BSEG, 256, 0, stream>>>(offsets, seg);
    prep_weights<<<(HDIM * 32 + HDIM * HDIM) / 256, 256, 0, stream>>>(W1, W2, w1t, w2t);
    fused_phi_pool<<<NWG, 256, 0, stream>>>(z, w1t, w2t,
                                            b1, g1, be1, b2, g2, be2,
                                            seg, sums_h);
    emb_gemm<<<BSEG / 2, 256, 0, stream>>>(sums_h, W3, b3, counts, emb);
    broadcast_out<<<NPTS * 32 / 256, 256, 0, stream>>>(emb, seg, out);
}

// Round 3
// 1031.998 us; speedup vs baseline: 1.2567x; 1.0352x over previous
//
#include <hip/hip_runtime.h>
#include <hip/hip_bf16.h>
#include <cstdint>
#include <cstddef>

// Problem constants (from reference)
#define NPTS  1000000
#define BSEG  2000
#define DIN   16
#define HDIM  256
#define DOUT  128
#define NTILE (NPTS / 32)   // 31250 tiles of 32 points
#define NWG   512           // persistent workgroups (2/CU)

typedef __bf16          bf16x8 __attribute__((ext_vector_type(8)));
typedef unsigned short  us16x8 __attribute__((ext_vector_type(8)));
typedef unsigned int    u32x4  __attribute__((ext_vector_type(4)));
typedef float           f32x4  __attribute__((ext_vector_type(4)));

static __device__ __forceinline__ unsigned short f2bf(float x) {
    unsigned int u = __float_as_uint(x);
    u += 0x7fffu + ((u >> 16) & 1u);
    return (unsigned short)(u >> 16);
}

static __device__ __forceinline__ bf16x8 ldb8(const unsigned short* p) {
    u32x4 v = *(const u32x4*)p;
    return __builtin_bit_cast(bf16x8, v);
}
static __device__ __forceinline__ f32x4 mfma16(bf16x8 a, bf16x8 b, f32x4 c) {
    return __builtin_amdgcn_mfma_f32_16x16x32_bf16(a, b, c, 0, 0, 0);
}
static __device__ __forceinline__ void keep(bf16x8& v) {
    u32x4 u = __builtin_bit_cast(u32x4, v);
    unsigned a0 = u[0], a1 = u[1], a2 = u[2], a3 = u[3];
    asm volatile("" : "+v"(a0), "+v"(a1), "+v"(a2), "+v"(a3));
    u32x4 r; r[0] = a0; r[1] = a1; r[2] = a2; r[3] = a3;
    v = __builtin_bit_cast(bf16x8, r);
}

// Sum across the 16 lanes of a DPP row (lanes quad*16..quad*16+15) using
// row_ror 8/4/2/1 — VALU-pipe (~4cyc/step) instead of ds_bpermute (~60cyc).
// All 16 lanes end with the full row sum.
static __device__ __forceinline__ float rsum16(float x) {
    x += __builtin_bit_cast(float, __builtin_amdgcn_update_dpp(
             0, __builtin_bit_cast(int, x), 0x128, 0xf, 0xf, false)); // ror:8
    x += __builtin_bit_cast(float, __builtin_amdgcn_update_dpp(
             0, __builtin_bit_cast(int, x), 0x124, 0xf, 0xf, false)); // ror:4
    x += __builtin_bit_cast(float, __builtin_amdgcn_update_dpp(
             0, __builtin_bit_cast(int, x), 0x122, 0xf, 0xf, false)); // ror:2
    x += __builtin_bit_cast(float, __builtin_amdgcn_update_dpp(
             0, __builtin_bit_cast(int, x), 0x121, 0xf, 0xf, false)); // ror:1
    return x;
}

// ---------------------------------------------------------------------------
__global__ __launch_bounds__(1024) void scan_counts(const int* __restrict__ counts,
                                                    int* __restrict__ offsets) {
    __shared__ int a[2048];
    const int t = threadIdx.x;
    a[t]        = (t        < BSEG) ? counts[t]        : 0;
    a[t + 1024] = (t + 1024 < BSEG) ? counts[t + 1024] : 0;
    for (int s = 1; s < 2048; s <<= 1) {
        __syncthreads();
        int x1 = (t >= s) ? a[t - s] : 0;
        int x2 = a[t + 1024 - s];
        __syncthreads();
        a[t] += x1;
        a[t + 1024] += x2;
    }
    __syncthreads();
    if (t == 0) offsets[0] = 0;
    offsets[t + 1] = a[t];
    if (t + 1024 < BSEG) offsets[t + 1025] = a[t + 1024];
}

__global__ __launch_bounds__(256) void fill_seg(const int* __restrict__ offsets,
                                                unsigned short* __restrict__ seg) {
    const int b  = blockIdx.x;
    const int lo = offsets[b], hi = offsets[b + 1];
    for (int i = lo + threadIdx.x; i < hi; i += 256) seg[i] = (unsigned short)b;
}

// W1T [256][32] (K zero-padded 16->32), W2T [256][256]; [n][k]-major bf16.
__global__ __launch_bounds__(256) void prep_weights(const float* __restrict__ W1,
                                                    const float* __restrict__ W2,
                                                    unsigned short* __restrict__ w1t,
                                                    unsigned short* __restrict__ w2t) {
    const int i = blockIdx.x * 256 + threadIdx.x;
    if (i < HDIM * 32) {
        int n = i >> 5, k = i & 31;
        w1t[i] = (k < DIN) ? f2bf(W1[k * HDIM + n]) : (unsigned short)0;
    } else {
        int j = i - HDIM * 32;
        if (j < HDIM * HDIM) {
            int n = j >> 8, k = j & 255;
            w2t[j] = f2bf(W2[k * HDIM + n]);
        }
    }
}

// ---------------------------------------------------------------------------
// Persistent fused kernel. Tile M=32 points, 4 waves; wave w owns cols
// [w*64, w*64+64). Weights register-resident; LN reductions via DPP row_ror;
// z software-pipelined one tile ahead (hides ~900cyc HBM latency).
// MFMA layouts: A[m=lane&15][k=quad*8+j]; B[k=quad*8+j][n=lane&15];
// D[row=quad*4+reg][col=lane&15].
// ---------------------------------------------------------------------------
__global__ __launch_bounds__(256, 2) void fused_phi_pool(
    const float* __restrict__ z,
    const unsigned short* __restrict__ w1t,
    const unsigned short* __restrict__ w2t,
    const float* __restrict__ b1, const float* __restrict__ g1, const float* __restrict__ be1,
    const float* __restrict__ b2, const float* __restrict__ g2, const float* __restrict__ be2,
    const unsigned short* __restrict__ seg,
    float* __restrict__ sums_h) {
    __shared__ __align__(16) unsigned short h1[32][264];   // 16.9 KB
    __shared__ __align__(16) float part[2][32][8];
    __shared__ __align__(16) int seg_sm[2][32];

    const int tid  = threadIdx.x;
    const int wave = tid >> 6;
    const int lane = tid & 63;
    const int l15  = lane & 15;
    const int quad = lane >> 4;
    const int colw = wave * 64 + l15;
    const bool zlane = (quad < 2);   // only k<16 lanes carry layer-1 A data

    // ---- one-time: register-resident weight fragments ----
    bf16x8 bw1[4];
    bf16x8 bw2[4][8];
#pragma unroll
    for (int t = 0; t < 4; ++t) {
        const int n = (wave * 4 + t) * 16 + l15;
        bw1[t] = ldb8(w1t + n * 32 + quad * 8);
        keep(bw1[t]);
#pragma unroll
        for (int ks = 0; ks < 8; ++ks) {
            bw2[t][ks] = ldb8(w2t + n * 256 + ks * 32 + quad * 8);
            keep(bw2[t][ks]);
        }
    }
    float b1v[4], g1v[4], e1v[4], b2v[4], g2v[4], e2v[4];
#pragma unroll
    for (int t = 0; t < 4; ++t) {
        const int c = colw + t * 16;
        b1v[t] = b1[c]; g1v[t] = g1[c]; e1v[t] = be1[c];
        b2v[t] = b2[c]; g2v[t] = g2[c]; e2v[t] = be2[c];
    }

    // ---- z prefetch pipeline (one tile ahead, registers only) ----
    float4 zn[2][2];   // [mb][half] raw fp32, valid on zlane only
    {
        const int base0 = blockIdx.x * 32;
        if (zlane) {
#pragma unroll
            for (int mb = 0; mb < 2; ++mb) {
                const float* zp = z + (size_t)(base0 + mb * 16 + l15) * DIN + quad * 8;
                zn[mb][0] = *(const float4*)zp;
                zn[mb][1] = *(const float4*)(zp + 4);
            }
        }
    }

    int p = 0;
    for (int tile = blockIdx.x; tile < NTILE; tile += NWG, p ^= 1) {
        const int base = tile * 32;
        if (tid < 32) seg_sm[p][tid] = (int)seg[base + tid];

        float4 zc[2][2];
#pragma unroll
        for (int mb = 0; mb < 2; ++mb) { zc[mb][0] = zn[mb][0]; zc[mb][1] = zn[mb][1]; }
        const int ntile = tile + NWG;
        if (zlane && ntile < NTILE) {
            const int nb = ntile * 32;
#pragma unroll
            for (int mb = 0; mb < 2; ++mb) {
                const float* zp = z + (size_t)(nb + mb * 16 + l15) * DIN + quad * 8;
                zn[mb][0] = *(const float4*)zp;
                zn[mb][1] = *(const float4*)(zp + 4);
            }
        }

        // ---------------- layer 1 (K=16 zero-padded to 32) ----------------
        f32x4 a1[2][4];
#pragma unroll
        for (int mb = 0; mb < 2; ++mb) {
            bf16x8 af;
            if (zlane) {
                us16x8 u;
                u[0] = f2bf(zc[mb][0].x); u[1] = f2bf(zc[mb][0].y);
                u[2] = f2bf(zc[mb][0].z); u[3] = f2bf(zc[mb][0].w);
                u[4] = f2bf(zc[mb][1].x); u[5] = f2bf(zc[mb][1].y);
                u[6] = f2bf(zc[mb][1].z); u[7] = f2bf(zc[mb][1].w);
                af = __builtin_bit_cast(bf16x8, u);
            } else {
                us16x8 u = {0, 0, 0, 0, 0, 0, 0, 0};
                af = __builtin_bit_cast(bf16x8, u);
            }
            const f32x4 zero = {0.f, 0.f, 0.f, 0.f};
#pragma unroll
            for (int t = 0; t < 4; ++t) a1[mb][t] = mfma16(af, bw1[t], zero);
        }
        // bias + LN stats partials (per-row sum/sumsq over this wave's 64 cols)
#pragma unroll
        for (int mb = 0; mb < 2; ++mb) {
            float s[4], q[4];
#pragma unroll
            for (int r = 0; r < 4; ++r) {
                float sv = 0.f, qv = 0.f;
#pragma unroll
                for (int t = 0; t < 4; ++t) {
                    float y = a1[mb][t][r] + b1v[t];
                    a1[mb][t][r] = y;
                    sv += y; qv += y * y;
                }
                s[r] = rsum16(sv); q[r] = rsum16(qv);
            }
            if (l15 == 0) {
#pragma unroll
                for (int r = 0; r < 4; ++r)
                    *(float2*)&part[p][mb * 16 + quad * 4 + r][wave * 2] =
                        make_float2(s[r], q[r]);
            }
        }
        __syncthreads();   // B1: stats visible; prior-iter h1 readers done
#pragma unroll
        for (int mb = 0; mb < 2; ++mb) {
#pragma unroll
            for (int r = 0; r < 4; ++r) {
                const int row = mb * 16 + quad * 4 + r;
                float4 pa = *(const float4*)&part[p][row][0];
                float4 pb = *(const float4*)&part[p][row][4];
                float st = pa.x + pa.z + pb.x + pb.z;
                float qt = pa.y + pa.w + pb.y + pb.w;
                float mean = st * (1.f / 256.f);
                float var  = qt * (1.f / 256.f) - mean * mean;
                float rs   = rsqrtf(fmaxf(var, 0.f) + 1e-5f);
#pragma unroll
                for (int t = 0; t < 4; ++t) {
                    float A = rs * g1v[t];
                    float y = fmaxf(fmaf(a1[mb][t][r], A, fmaf(-mean, A, e1v[t])), 0.f);
                    h1[row][colw + t * 16] = f2bf(y);
                }
            }
        }
        __syncthreads();   // B2: h1 ready

        // ---------------- layer 2 ----------------
        f32x4 a2[2][4];
#pragma unroll
        for (int mb = 0; mb < 2; ++mb) {
            const f32x4 zero = {0.f, 0.f, 0.f, 0.f};
#pragma unroll
            for (int t = 0; t < 4; ++t) a2[mb][t] = zero;
#pragma unroll
            for (int ks = 0; ks < 8; ++ks) {
                bf16x8 af = ldb8(&h1[mb * 16 + l15][ks * 32 + quad * 8]);
#pragma unroll
                for (int t = 0; t < 4; ++t) a2[mb][t] = mfma16(af, bw2[t][ks], a2[mb][t]);
            }
        }
#pragma unroll
        for (int mb = 0; mb < 2; ++mb) {
            float s[4], q[4];
#pragma unroll
            for (int r = 0; r < 4; ++r) {
                float sv = 0.f, qv = 0.f;
#pragma unroll
                for (int t = 0; t < 4; ++t) {
                    float y = a2[mb][t][r] + b2v[t];
                    a2[mb][t][r] = y;
                    sv += y; qv += y * y;
                }
                s[r] = rsum16(sv); q[r] = rsum16(qv);
            }
            if (l15 == 0) {
#pragma unroll
                for (int r = 0; r < 4; ++r)
                    *(float2*)&part[p][mb * 16 + quad * 4 + r][wave * 2] =
                        make_float2(s[r], q[r]);
            }
        }
        __syncthreads();   // B3: layer-2 stats visible
#pragma unroll
        for (int mb = 0; mb < 2; ++mb) {
#pragma unroll
            for (int r = 0; r < 4; ++r) {
                const int row = mb * 16 + quad * 4 + r;
                float4 pa = *(const float4*)&part[p][row][0];
                float4 pb = *(const float4*)&part[p][row][4];
                float st = pa.x + pa.z + pb.x + pb.z;
                float qt = pa.y + pa.w + pb.y + pb.w;
                float mean = st * (1.f / 256.f);
                float var  = qt * (1.f / 256.f) - mean * mean;
                float rs   = rsqrtf(fmaxf(var, 0.f) + 1e-5f);
#pragma unroll
                for (int t = 0; t < 4; ++t) {
                    float A = rs * g2v[t];
                    a2[mb][t][r] =
                        fmaxf(fmaf(a2[mb][t][r], A, fmaf(-mean, A, e2v[t])), 0.f);
                }
            }
        }

        // ---------------- ragged segment-sum of h2 (fp32) ----------------
        const int s0  = seg_sm[p][0];
        const int s31 = seg_sm[p][31];
        if (s0 == s31) {   // tile entirely inside one segment (~94%)
#pragma unroll
            for (int t = 0; t < 4; ++t) {
                float cs = a2[0][t][0] + a2[0][t][1] + a2[0][t][2] + a2[0][t][3]
                         + a2[1][t][0] + a2[1][t][1] + a2[1][t][2] + a2[1][t][3];
                cs += __shfl_xor(cs, 16, 64);
                cs += __shfl_xor(cs, 32, 64);
                if (quad == 0)
                    atomicAdd(&sums_h[s0 * HDIM + colw + t * 16], cs);
            }
        } else {           // exactly 2 segments (min count 100 > 32)
            const int* sgp = &seg_sm[p][0];
            float m0[4], m1[4];
#pragma unroll
            for (int r = 0; r < 4; ++r) {
                m0[r] = (sgp[quad * 4 + r]      == s0) ? 1.f : 0.f;
                m1[r] = (sgp[16 + quad * 4 + r] == s0) ? 1.f : 0.f;
            }
#pragma unroll
            for (int t = 0; t < 4; ++t) {
                float cs = 0.f, ca = 0.f;
#pragma unroll
                for (int r = 0; r < 4; ++r) {
                    cs += a2[0][t][r] + a2[1][t][r];
                    ca = fmaf(a2[0][t][r], m0[r], ca);
                    ca = fmaf(a2[1][t][r], m1[r], ca);
                }
                cs += __shfl_xor(cs, 16, 64);
                cs += __shfl_xor(cs, 32, 64);
                ca += __shfl_xor(ca, 16, 64);
                ca += __shfl_xor(ca, 32, 64);
                if (quad == 0) {
                    atomicAdd(&sums_h[s0  * HDIM + colw + t * 16], ca);
                    atomicAdd(&sums_h[s31 * HDIM + colw + t * 16], cs - ca);
                }
            }
        }
    }
}

// ---------------------------------------------------------------------------
// emb[b] = (sums_h[b] @ W3) / count_b + b3
// ---------------------------------------------------------------------------
__global__ __launch_bounds__(256) void emb_gemm(const float* __restrict__ sums_h,
                                                const float* __restrict__ W3,
                                                const float* __restrict__ b3,
                                                const int* __restrict__ counts,
                                                float* __restrict__ emb) {
    const int b = blockIdx.x * 2 + (threadIdx.x >> 7);
    const int o = threadIdx.x & 127;
    const float* sh = sums_h + b * HDIM;
    float acc = 0.f;
#pragma unroll 8
    for (int k = 0; k < HDIM; ++k) acc = fmaf(sh[k], W3[k * DOUT + o], acc);
    emb[b * DOUT + o] = acc / (float)counts[b] + b3[o];
}

// ---------------------------------------------------------------------------
// out[n] = emb[seg[n]] ; 32 B/thread coalesced stores
// ---------------------------------------------------------------------------
__global__ __launch_bounds__(256) void broadcast_out(const float* __restrict__ emb,
                                                     const unsigned short* __restrict__ seg,
                                                     float* __restrict__ out) {
    const int idx = blockIdx.x * 256 + threadIdx.x;   // n*16 + oct, exactly N*16
    const int n = idx >> 4, oct = idx & 15;
    const int s = seg[n];
    float4 v0 = ((const float4*)emb)[s * 32 + oct * 2];
    float4 v1 = ((const float4*)emb)[s * 32 + oct * 2 + 1];
    ((float4*)out)[idx * 2]     = v0;
    ((float4*)out)[idx * 2 + 1] = v1;
}

// ---------------------------------------------------------------------------
extern "C" void kernel_launch(void* const* d_in, const int* in_sizes, int n_in,
                              void* d_out, int out_size, void* d_ws, size_t ws_size,
                              hipStream_t stream) {
    const float* z   = (const float*)d_in[0];
    const float* W1  = (const float*)d_in[1];
    const float* b1  = (const float*)d_in[2];
    const float* g1  = (const float*)d_in[3];
    const float* be1 = (const float*)d_in[4];
    const float* W2  = (const float*)d_in[5];
    const float* b2  = (const float*)d_in[6];
    const float* g2  = (const float*)d_in[7];
    const float* be2 = (const float*)d_in[8];
    const float* W3  = (const float*)d_in[9];
    const float* b3  = (const float*)d_in[10];
    const int* counts = (const int*)d_in[11];
    float* out = (float*)d_out;

    char* ws = (char*)d_ws;
    float*          sums_h  = (float*)(ws);                     // 2,048,000 B
    float*          emb     = (float*)(ws + 2048000);           // 1,024,000 B
    int*            offsets = (int*)  (ws + 3072000);           //     8,016 B
    unsigned short* seg     = (unsigned short*)(ws + 3080016);  // 2,000,000 B
    unsigned short* w1t     = (unsigned short*)(ws + 5080016);  //    16,384 B
    unsigned short* w2t     = (unsigned short*)(ws + 5096400);  //   131,072 B

    hipMemsetAsync(sums_h, 0, (size_t)BSEG * HDIM * sizeof(float), stream);
    scan_counts<<<1, 1024, 0, stream>>>(counts, offsets);
    fill_seg<<<BSEG, 256, 0, stream>>>(offsets, seg);
    prep_weights<<<(HDIM * 32 + HDIM * HDIM) / 256, 256, 0, stream>>>(W1, W2, w1t, w2t);
    fused_phi_pool<<<NWG, 256, 0, stream>>>(z, w1t, w2t,
                                            b1, g1, be1, b2, g2, be2,
                                            seg, sums_h);
    emb_gemm<<<BSEG / 2, 256, 0, stream>>>(sums_h, W3, b3, counts, emb);
    broadcast_out<<<NPTS * 16 / 256, 256, 0, stream>>>(emb, seg, out);
}